// Round 3
// baseline (7125.938 us; speedup 1.0000x reference)
//
#include <hip/hip_runtime.h>
#include <hip/hip_bf16.h>

constexpr int NB   = 2048;
constexpr int NE   = 30;   // electrons
constexpr int NN   = 8;    // nuclei
constexpr int NA   = 38;   // all
constexpr int BAS  = 32;
constexpr int KD   = 64;
constexpr int ED   = 128;
constexpr int HK   = 45;
constexpr int HO   = 91;
constexpr int LNUM = 3;
constexpr int P    = NE * (NA - 1);   // 1110
constexpr int CHUNK = 128;
constexpr int NCH   = 9;              // 9*128 = 1152 >= 1110

__device__ __forceinline__ float ssp(float x) {
    // softplus(x) - ln 2, stable (matches jax.nn.softplus - log 2)
    float sp = fmaxf(x, 0.f) + log1pf(expf(-fabsf(x)));
    return sp - 0.69314718055994530942f;
}

__global__ __launch_bounds__(256) void schnet_kernel(
    const float* __restrict__ dists,  // B,NE,NA,BAS  (fp32)
    const float* __restrict__ emb_e,  // NE,ED
    const float* __restrict__ emb_n,  // NN,KD
    const float* __restrict__ kw1,    // L,BAS,HK
    const float* __restrict__ kb1,    // L,HK
    const float* __restrict__ kw2,    // L,HK,KD
    const float* __restrict__ kb2,    // L,KD
    const float* __restrict__ ew,     // L,ED,KD
    const float* __restrict__ ow1,    // L,KD,HO
    const float* __restrict__ ob1,    // L,HO
    const float* __restrict__ ow2,    // L,HO,ED
    const float* __restrict__ ob2,    // L,ED
    float* __restrict__ out)          // B,NE,ED  (fp32 output — per reference)
{
    __shared__ float xs[NE * ED];          // 3840 f
    __shared__ float zs[NA * KD];          // 2432 f
    __shared__ float msg4[4 * 32 * KD];    // 8192 f (4 copies, 1 per wave)
    __shared__ float dbuf[CHUNK * BAS];    // 4096 f (reused as ho: 30*91=2730)
    __shared__ float hbuf[CHUNK * HK];     // 5760 f

    const int b = blockIdx.x;
    const int t = threadIdx.x;
    const float* db_b = dists + (size_t)b * NE * NA * BAS;

    // init xs from electron embeddings
    for (int o = t; o < NE * ED; o += 256) xs[o] = emb_e[o];
    // nuclear rows of zs (constant across layers)
    for (int o = t; o < NN * KD; o += 256) zs[NE * KD + o] = emb_n[o];
    __syncthreads();

    for (int l = 0; l < LNUM; ++l) {
        const float* w1 = kw1 + l * BAS * HK;
        const float* b1 = kb1 + l * HK;
        const float* w2 = kw2 + l * HK * KD;
        const float* b2 = kb2 + l * KD;
        const float* we = ew  + l * ED * KD;
        const float* o1 = ow1 + l * KD * HO;
        const float* g1 = ob1 + l * HO;
        const float* o2 = ow2 + l * HO * ED;
        const float* g2 = ob2 + l * ED;

        // zero msg copies
        for (int o = t; o < 4 * 32 * KD; o += 256) msg4[o] = 0.f;
        // zs rows 0..NE-1 : xs @ embed_in_w
        for (int o = t; o < NE * KD; o += 256) {
            int i = o >> 6, k = o & 63;
            float acc = 0.f;
            #pragma unroll 8
            for (int e = 0; e < ED; ++e)
                acc += xs[i * ED + e] * we[e * KD + k];
            zs[o] = acc;
        }
        __syncthreads();

        const int kk = t & 63, g = t >> 6;
        const float bb2 = b2[kk];

        for (int c = 0; c < NCH; ++c) {
            // stage db chunk (gathered pair rows) into LDS
            for (int o = t; o < CHUNK * BAS; o += 256) {
                int q = o >> 5, e = o & 31;
                int p = c * CHUNK + q;
                float v = 0.f;
                if (p < P) {
                    int i = p / 37;
                    int jj = p - i * 37;
                    int j = jj + (jj >= i ? 1 : 0);
                    v = db_b[(i * NA + j) * BAS + e];
                }
                dbuf[o] = v;
            }
            __syncthreads();

            // H = ssp(db @ W1 + b1), 4 pairs per work item
            for (int it = t; it < (CHUNK / 4) * HK; it += 256) {
                int q0 = (it / HK) * 4;
                int h  = it - (it / HK) * HK;
                float bb = b1[h];
                float a0 = bb, a1 = bb, a2 = bb, a3 = bb;
                #pragma unroll
                for (int e = 0; e < BAS; ++e) {
                    float w = w1[e * HK + h];
                    a0 += dbuf[(q0 + 0) * BAS + e] * w;
                    a1 += dbuf[(q0 + 1) * BAS + e] * w;
                    a2 += dbuf[(q0 + 2) * BAS + e] * w;
                    a3 += dbuf[(q0 + 3) * BAS + e] * w;
                }
                hbuf[(q0 + 0) * HK + h] = ssp(a0);
                hbuf[(q0 + 1) * HK + h] = ssp(a1);
                hbuf[(q0 + 2) * HK + h] = ssp(a2);
                hbuf[(q0 + 3) * HK + h] = ssp(a3);
            }
            __syncthreads();

            // Ws = H @ W2 + b2 ; msg[i] += Ws * zs[j]   (4 q per step, copy g)
            for (int s = 0; s < CHUNK / 16; ++s) {
                int q0 = g + 16 * s;           // pairs q0, q0+4, q0+8, q0+12
                int iu[4], ju[4];
                float a[4];
                #pragma unroll
                for (int u = 0; u < 4; ++u) {
                    int p = c * CHUNK + (q0 + 4 * u);
                    int i, j;
                    if (p < P) {
                        i = p / 37;
                        int jj = p - i * 37;
                        j = jj + (jj >= i ? 1 : 0);
                    } else { i = 30; j = 0; }
                    iu[u] = i; ju[u] = j; a[u] = bb2;
                }
                #pragma unroll
                for (int h = 0; h < HK; ++h) {
                    float w = w2[h * KD + kk];
                    a[0] += hbuf[(q0 +  0) * HK + h] * w;
                    a[1] += hbuf[(q0 +  4) * HK + h] * w;
                    a[2] += hbuf[(q0 +  8) * HK + h] * w;
                    a[3] += hbuf[(q0 + 12) * HK + h] * w;
                }
                #pragma unroll
                for (int u = 0; u < 4; ++u) {
                    float val = a[u] * zs[ju[u] * KD + kk];
                    msg4[(g * 32 + iu[u]) * KD + kk] += val;
                }
            }
            __syncthreads();
        }

        // reduce 4 msg copies into msg (= msg4[0..])
        for (int o = t; o < NE * KD; o += 256) {
            float m = msg4[o] + msg4[32 * KD + o] + msg4[2 * 32 * KD + o]
                    + msg4[3 * 32 * KD + o];
            msg4[o] = m;
        }
        __syncthreads();

        // out-net part 1: ho = ssp(msg @ out_w1 + out_b1)   (30 x 91)
        float* ho = dbuf;  // reuse
        for (int o = t; o < NE * HO; o += 256) {
            int i = o / HO, h = o - (o / HO) * HO;
            float acc = g1[h];
            #pragma unroll 8
            for (int m = 0; m < KD; ++m)
                acc += msg4[i * KD + m] * o1[m * HO + h];
            ho[o] = ssp(acc);
        }
        __syncthreads();

        // out-net part 2: xs += ho @ out_w2 + out_b2   (30 x 128)
        for (int o = t; o < NE * ED; o += 256) {
            int i = o >> 7, k2 = o & 127;
            float acc = g2[k2];
            #pragma unroll 7
            for (int h = 0; h < HO; ++h)
                acc += ho[i * HO + h] * o2[h * ED + k2];
            xs[o] += acc;
        }
        __syncthreads();
    }

    for (int o = t; o < NE * ED; o += 256)
        out[(size_t)b * NE * ED + o] = xs[o];
}

extern "C" void kernel_launch(void* const* d_in, const int* in_sizes, int n_in,
                              void* d_out, int out_size, void* d_ws, size_t ws_size,
                              hipStream_t stream) {
    const float* dists = (const float*)d_in[0];
    const float* emb_e = (const float*)d_in[1];
    const float* emb_n = (const float*)d_in[2];
    const float* kw1   = (const float*)d_in[3];
    const float* kb1   = (const float*)d_in[4];
    const float* kw2   = (const float*)d_in[5];
    const float* kb2   = (const float*)d_in[6];
    const float* ew    = (const float*)d_in[7];
    const float* ow1   = (const float*)d_in[8];
    const float* ob1   = (const float*)d_in[9];
    const float* ow2   = (const float*)d_in[10];
    const float* ob2   = (const float*)d_in[11];
    float* out = (float*)d_out;

    schnet_kernel<<<NB, 256, 0, stream>>>(dists, emb_e, emb_n, kw1, kb1, kw2, kb2,
                                          ew, ow1, ob1, ow2, ob2, out);
}

// Round 4
// 1800.448 us; speedup vs baseline: 3.9579x; 3.9579x over previous
//
#include <hip/hip_runtime.h>
#include <hip/hip_bf16.h>

typedef __attribute__((ext_vector_type(8))) short bf16x8;
typedef __attribute__((ext_vector_type(4))) float f32x4;

constexpr int NB = 2048;
constexpr int NE = 30, NN = 8, NAll = 38;
constexpr int BAS = 32, KD = 64, ED = 128, HK = 45, HO = 91, LNUM = 3;
constexpr int NCHUNK = 19;          // 19 chunks * 64 rows = 1216 = 38 j * 32 i(pad)

__device__ __forceinline__ unsigned short f2b(float v) {
    __hip_bfloat16 h = __float2bfloat16(v);
    return __builtin_bit_cast(unsigned short, h);
}
__device__ __forceinline__ float ssp(float x) {
    float e = __expf(-fabsf(x));
    return fmaxf(x, 0.f) + __logf(1.f + e) - 0.69314718055994530942f;
}
// XOR-swizzled element index: 8-elem blocks permuted within a row by row-low-bits.
// S (elems/row) must be a power-of-2 multiple of 8. Writers and readers agree.
__device__ __forceinline__ int swzi(int row, int col, int S) {
    int mask = (S >> 3) - 1;
    int blk = ((col >> 3) ^ row) & mask;
    return row * S + (blk << 3) + (col & 7);
}
// MFMA fragment load (A from [m][k], B from Bt[n][k]); col must be 8-aligned.
__device__ __forceinline__ bf16x8 ldfrag(const unsigned short* p, int S, int row, int col) {
    int mask = (S >> 3) - 1;
    int blk = ((col >> 3) ^ row) & mask;
    return *(const bf16x8*)(p + row * S + (blk << 3));
}

__global__ __launch_bounds__(256) void schnet_mfma(
    const float* __restrict__ dists,
    const float* __restrict__ emb_e,
    const float* __restrict__ emb_n,
    const float* __restrict__ kw1, const float* __restrict__ kb1,
    const float* __restrict__ kw2, const float* __restrict__ kb2,
    const float* __restrict__ ew,
    const float* __restrict__ ow1, const float* __restrict__ ob1,
    const float* __restrict__ ow2, const float* __restrict__ ob2,
    float* __restrict__ out)
{
    // 49 KB LDS -> 3 blocks/CU
    __shared__ __align__(16) unsigned char smem[50240];
    float* xs  = (float*)smem;              // [30][128] fp32, persistent
    float* zsb = (float*)(smem + 15360);    // [38][64]  fp32
    float* b1s = (float*)(smem + 25088);    // [48]
    float* g1s = (float*)(smem + 25280);    // [96]
    unsigned char* U = smem + 25664;        // 24576 B phase-union scratch

    const int b = blockIdx.x;
    const int t = threadIdx.x;
    const int lane = t & 63, wv = t >> 6;
    const int q = lane >> 4, cc = lane & 15;
    const float* db_b = dists + (size_t)b * NE * NAll * BAS;

    for (int o = t; o < NE * ED; o += 256) xs[o] = emb_e[o];
    for (int o = t; o < NN * KD; o += 256) zsb[NE * KD + o] = emb_n[o];  // nuc rows, constant
    __syncthreads();

    for (int l = 0; l < LNUM; ++l) {
        const float* w1g = kw1 + l * BAS * HK;
        const float* b1g = kb1 + l * HK;
        const float* w2g = kw2 + l * HK * KD;
        const float* b2g = kb2 + l * KD;
        const float* weg = ew  + l * ED * KD;
        const float* o1g = ow1 + l * KD * HO;
        const float* g1g = ob1 + l * HO;
        const float* o2g = ow2 + l * HO * ED;
        const float* g2g = ob2 + l * ED;

        // ================= zs phase: zs[0:30] = xs @ embed_in_w =================
        {
            unsigned short* wet  = (unsigned short*)U;             // Bt [k=64][e=128]
            unsigned short* xsbf = (unsigned short*)(U + 16384);   // A  [32][128]
            for (int o = t; o < 64 * 128; o += 256) {
                int k = o & 63, e = o >> 6;                        // coalesced over k
                wet[swzi(k, e, 128)] = f2b(weg[e * 64 + k]);
            }
            for (int o = t; o < 32 * 128; o += 256) {
                int r = o >> 7, c2 = o & 127;
                float v = (r < NE) ? xs[r * 128 + c2] : 0.f;
                xsbf[swzi(r, c2, 128)] = f2b(v);
            }
            __syncthreads();
            #pragma unroll
            for (int mt = 0; mt < 2; ++mt) {
                f32x4 acc = {0.f, 0.f, 0.f, 0.f};
                #pragma unroll
                for (int ks = 0; ks < 4; ++ks)
                    acc = __builtin_amdgcn_mfma_f32_16x16x32_bf16(
                        ldfrag(xsbf, 128, mt * 16 + cc, ks * 32 + q * 8),
                        ldfrag(wet, 128, wv * 16 + cc, ks * 32 + q * 8), acc, 0, 0, 0);
                #pragma unroll
                for (int r = 0; r < 4; ++r) {
                    int row = mt * 16 + q * 4 + r;
                    if (row < NE) zsb[row * 64 + wv * 16 + cc] = acc[r];
                }
            }
            __syncthreads();
        }

        // ================= pair phase: Ws = ssp(db@W1+b1)@W2+b2; msg += Ws*zs[j] ==
        float msgreg[8] = {0, 0, 0, 0, 0, 0, 0, 0};   // msg[i][col]: i = h*16+q*4+r, col = wv*16+cc
        {
            unsigned short* w1t = (unsigned short*)U;             // Bt [h=48][e=32]
            unsigned short* w2t = (unsigned short*)(U + 3072);    // Bt [k=64][h=64pad]
            unsigned short* dbA = (unsigned short*)(U + 11264);   // A  [64][32]
            unsigned short* Hb  = (unsigned short*)(U + 15360);   // A  [64][64pad]
            for (int o = t; o < 48 * 32; o += 256) {
                int h = o % 48, e = o / 48;                       // coalesced over h
                float v = (h < HK) ? w1g[e * HK + h] : 0.f;
                w1t[swzi(h, e, 32)] = f2b(v);
            }
            for (int o = t; o < 64 * 64; o += 256) {
                int k = o & 63, h = o >> 6;                       // coalesced over k
                float v = (h < HK) ? w2g[h * 64 + k] : 0.f;
                w2t[swzi(k, h, 64)] = f2b(v);
            }
            for (int o = t; o < 64 * 64; o += 256) Hb[o] = 0;     // zero incl. pad cols
            if (t < 48) b1s[t] = (t < HK) ? b1g[t] : 0.f;
            const float b2v = b2g[wv * 16 + cc];
            __syncthreads();
            bf16x8 wb0 = ldfrag(w2t, 64, wv * 16 + cc, q * 8);
            bf16x8 wb1 = ldfrag(w2t, 64, wv * 16 + cc, 32 + q * 8);

            for (int ch = 0; ch < NCHUNK; ++ch) {
                int jbase = ch * 2;
                // stage 64 pair rows: row = (j-jbase)*32 + i
                for (int o = t; o < 2048; o += 256) {
                    int row = o >> 5, e = o & 31;
                    int i = row & 31, j = jbase + (row >> 5);
                    float v = (i < NE) ? db_b[(i * NAll + j) * BAS + e] : 0.f;
                    dbA[swzi(row, e, 32)] = f2b(v);
                }
                __syncthreads();
                // GEMM1 [64x32]@[32x48] + ssp -> Hb
                #pragma unroll
                for (int s = 0; s < 3; ++s) {
                    int tid = wv + 4 * s, mt = tid & 3, nt = tid >> 2;
                    f32x4 acc = {0.f, 0.f, 0.f, 0.f};
                    acc = __builtin_amdgcn_mfma_f32_16x16x32_bf16(
                        ldfrag(dbA, 32, mt * 16 + cc, q * 8),
                        ldfrag(w1t, 32, nt * 16 + cc, q * 8), acc, 0, 0, 0);
                    int col = nt * 16 + cc;
                    float b1v = b1s[col];
                    #pragma unroll
                    for (int r = 0; r < 4; ++r) {
                        int row = mt * 16 + q * 4 + r;
                        float vv = ssp(acc[r] + b1v);
                        if (col < HK) Hb[swzi(row, col, 64)] = f2b(vv);
                    }
                }
                __syncthreads();
                // GEMM2 [64x48]@[48x64]; epilogue: msgreg += (Ws+b2)*zs[j]
                #pragma unroll
                for (int mt = 0; mt < 4; ++mt) {
                    f32x4 acc = {0.f, 0.f, 0.f, 0.f};
                    acc = __builtin_amdgcn_mfma_f32_16x16x32_bf16(
                        ldfrag(Hb, 64, mt * 16 + cc, q * 8), wb0, acc, 0, 0, 0);
                    acc = __builtin_amdgcn_mfma_f32_16x16x32_bf16(
                        ldfrag(Hb, 64, mt * 16 + cc, 32 + q * 8), wb1, acc, 0, 0, 0);
                    int j = jbase + (mt >> 1);
                    float zsv = zsb[j * 64 + wv * 16 + cc];   // broadcast per quad
                    int half = mt & 1;
                    #pragma unroll
                    for (int r = 0; r < 4; ++r) {
                        int i = half * 16 + q * 4 + r;
                        float val = (acc[r] + b2v) * zsv;
                        if (i < NE && j != i) msgreg[half * 4 + r] += val;
                    }
                }
                __syncthreads();
            }
        }

        // ================= out phase: xs += ssp(msg@o1+b1o)@o2+b2o ===============
        {
            unsigned short* hob  = (unsigned short*)U;            // A [32][128pad]
            unsigned short* msgb = (unsigned short*)(U + 8192);   // A [32][64]
            unsigned short* o1t  = (unsigned short*)(U + 12288);  // Bt [h=96][m=64]
            #pragma unroll
            for (int half = 0; half < 2; ++half)
                #pragma unroll
                for (int r = 0; r < 4; ++r) {
                    int i = half * 16 + q * 4 + r;
                    float v = (i < NE) ? msgreg[half * 4 + r] : 0.f;
                    msgb[swzi(i, wv * 16 + cc, 64)] = f2b(v);
                }
            for (int o = t; o < 6144; o += 256) {
                int h = o % 96, m = o / 96;                       // coalesced over h
                float v = (h < HO) ? o1g[m * HO + h] : 0.f;
                o1t[swzi(h, m, 64)] = f2b(v);
            }
            for (int o = t; o < 32 * 128; o += 256) hob[o] = 0;
            if (t < 96) g1s[t] = (t < HO) ? g1g[t] : 0.f;
            __syncthreads();
            // GEMM o1 [32x64]@[64x96] + ssp -> hob
            #pragma unroll
            for (int s = 0; s < 3; ++s) {
                int tid = wv + 4 * s, mt = tid & 1, nt = tid >> 1;
                f32x4 acc = {0.f, 0.f, 0.f, 0.f};
                #pragma unroll
                for (int ks = 0; ks < 2; ++ks)
                    acc = __builtin_amdgcn_mfma_f32_16x16x32_bf16(
                        ldfrag(msgb, 64, mt * 16 + cc, ks * 32 + q * 8),
                        ldfrag(o1t, 64, nt * 16 + cc, ks * 32 + q * 8), acc, 0, 0, 0);
                int col = nt * 16 + cc;
                float g1v = g1s[col];
                #pragma unroll
                for (int r = 0; r < 4; ++r) {
                    int row = mt * 16 + q * 4 + r;
                    float vv = ssp(acc[r] + g1v);
                    if (col < HO) hob[swzi(row, col, 128)] = f2b(vv);
                }
            }
            __syncthreads();
            // GEMM o2 [32x96]@[96x64] per half of ED; += into xs
            unsigned short* o2th = (unsigned short*)(U + 8192);   // Bt [e=64][h=128pad]
            #pragma unroll
            for (int ph = 0; ph < 2; ++ph) {
                for (int o = t; o < 8192; o += 256) {
                    int e = o & 63, h = o >> 6;                   // coalesced over e
                    float v = (h < HO) ? o2g[h * ED + ph * 64 + e] : 0.f;
                    o2th[swzi(e, h, 128)] = f2b(v);
                }
                __syncthreads();
                float g2v = g2g[ph * 64 + wv * 16 + cc];
                #pragma unroll
                for (int mt = 0; mt < 2; ++mt) {
                    f32x4 acc = {0.f, 0.f, 0.f, 0.f};
                    #pragma unroll
                    for (int ks = 0; ks < 3; ++ks)
                        acc = __builtin_amdgcn_mfma_f32_16x16x32_bf16(
                            ldfrag(hob, 128, mt * 16 + cc, ks * 32 + q * 8),
                            ldfrag(o2th, 128, wv * 16 + cc, ks * 32 + q * 8), acc, 0, 0, 0);
                    #pragma unroll
                    for (int r = 0; r < 4; ++r) {
                        int row = mt * 16 + q * 4 + r;
                        if (row < NE) xs[row * 128 + ph * 64 + wv * 16 + cc] += acc[r] + g2v;
                    }
                }
                __syncthreads();
            }
        }
    }
    for (int o = t; o < NE * ED; o += 256) out[(size_t)b * NE * ED + o] = xs[o];
}

extern "C" void kernel_launch(void* const* d_in, const int* in_sizes, int n_in,
                              void* d_out, int out_size, void* d_ws, size_t ws_size,
                              hipStream_t stream) {
    const float* dists = (const float*)d_in[0];
    const float* emb_e = (const float*)d_in[1];
    const float* emb_n = (const float*)d_in[2];
    const float* kw1   = (const float*)d_in[3];
    const float* kb1   = (const float*)d_in[4];
    const float* kw2   = (const float*)d_in[5];
    const float* kb2   = (const float*)d_in[6];
    const float* ew    = (const float*)d_in[7];
    const float* ow1   = (const float*)d_in[8];
    const float* ob1   = (const float*)d_in[9];
    const float* ow2   = (const float*)d_in[10];
    const float* ob2   = (const float*)d_in[11];
    float* out = (float*)d_out;

    schnet_mfma<<<NB, 256, 0, stream>>>(dists, emb_e, emb_n, kw1, kb1, kw2, kb2,
                                        ew, ow1, ob1, ow2, ob2, out);
}